// Round 5
// baseline (1020.280 us; speedup 1.0000x reference)
//
#include <hip/hip_runtime.h>
#include <hip/hip_fp16.h>
#include <math.h>

#define NN 500000
#define BSZ 512                      // nodes per bucket
#define NBK ((NN + BSZ - 1) / BSZ)   // 977 buckets
#define CHUNK 16384                  // edges per partition/hist block

typedef __attribute__((ext_vector_type(4))) _Float16 half4;
typedef __attribute__((ext_vector_type(2))) _Float16 half2v;
typedef __attribute__((ext_vector_type(4))) int int4v;   // clang vector: ok for nontemporal builtins

// ---------- pass 1: bucket histogram (LDS-staged) + per-block counts -------
__global__ void hist_kernel(const int* __restrict__ col, int* __restrict__ bucketCount,
                            int* __restrict__ blkCnt, int E) {
    __shared__ int cnt[1024];
    int t = threadIdx.x;
    for (int i = t; i < 1024; i += 256) cnt[i] = 0;
    __syncthreads();
    int base = blockIdx.x * CHUNK;
    int end = base + CHUNK; if (end > E) end = E;
    int j = base + t * 4;
    for (; j + 3 < end; j += 1024) {
        int4v c = __builtin_nontemporal_load(reinterpret_cast<const int4v*>(col + j));
        atomicAdd(&cnt[c.x >> 9], 1);
        atomicAdd(&cnt[c.y >> 9], 1);
        atomicAdd(&cnt[c.z >> 9], 1);
        atomicAdd(&cnt[c.w >> 9], 1);
    }
    if (j < end) for (int k = j; k < end; ++k) atomicAdd(&cnt[col[k] >> 9], 1);
    __syncthreads();
    int* myCnt = blkCnt + (size_t)blockIdx.x * 1024;
    for (int b = t; b < 1024; b += 256) {
        int c = cnt[b];
        myCnt[b] = c;
        if (c) atomicAdd(&bucketCount[b], c);
    }
}

// ---------- pass 2: exclusive scan of 1024 bucket counts (1 block) ---------
__global__ void scan_kernel(const int* __restrict__ bucketCount, int* __restrict__ bucketStart,
                            int* __restrict__ gcursor) {
    __shared__ int ls[1024];
    int t = threadIdx.x;
    int v = bucketCount[t];
    ls[t] = v;
    __syncthreads();
    for (int off = 1; off < 1024; off <<= 1) {
        int u = (t >= off) ? ls[t - off] : 0;
        __syncthreads();
        ls[t] += u;
        __syncthreads();
    }
    int excl = ls[t] - v;
    bucketStart[t] = excl;
    gcursor[t] = excl;
}

// ---------- pass 3: partition edges into buckets (chunk reservation) -------
__global__ void part_kernel(const int* __restrict__ row, const int* __restrict__ col,
                            int* __restrict__ gcursor, const int* __restrict__ blkCnt,
                            int* __restrict__ recs, int E) {
    __shared__ int cnt[1024];
    __shared__ int basex[1024];
    int t = threadIdx.x;
    // phase B: reserve contiguous space per bucket using hist's per-block counts
    const int* myCnt = blkCnt + (size_t)blockIdx.x * 1024;
    for (int b = t; b < 1024; b += 256) {
        int c = myCnt[b];
        basex[b] = c ? atomicAdd(&gcursor[b], c) : 0;
        cnt[b] = 0;
    }
    __syncthreads();
    int base = blockIdx.x * CHUNK;
    int end = base + CHUNK; if (end > E) end = E;
    // phase C: write packed records at reserved ranks
    int j = base + t * 4;
    for (; j + 3 < end; j += 1024) {
        int4v r = __builtin_nontemporal_load(reinterpret_cast<const int4v*>(row + j));
        int4v c = __builtin_nontemporal_load(reinterpret_cast<const int4v*>(col + j));
        int b, rk;
        b = c.x >> 9; rk = atomicAdd(&cnt[b], 1); recs[basex[b] + rk] = (r.x << 9) | (c.x & 511);
        b = c.y >> 9; rk = atomicAdd(&cnt[b], 1); recs[basex[b] + rk] = (r.y << 9) | (c.y & 511);
        b = c.z >> 9; rk = atomicAdd(&cnt[b], 1); recs[basex[b] + rk] = (r.z << 9) | (c.z & 511);
        b = c.w >> 9; rk = atomicAdd(&cnt[b], 1); recs[basex[b] + rk] = (r.w << 9) | (c.w & 511);
    }
    if (j < end) {
        for (int k = j; k < end; ++k) {
            int b = col[k] >> 9;
            int rk = atomicAdd(&cnt[b], 1);
            recs[basex[b] + rk] = (row[k] << 9) | (col[k] & 511);
        }
    }
}

// ---------- pass 4: per-bucket degree count -> dinv (no global atomics) ----
__global__ void deg_kernel(const int* __restrict__ bucketStart, const int* __restrict__ bucketCount,
                           const int* __restrict__ recs, float* __restrict__ dinv, int N) {
    __shared__ int cnt[BSZ];
    int t = threadIdx.x, b = blockIdx.x;
    for (int i = t; i < BSZ; i += 256) cnt[i] = 0;
    __syncthreads();
    int s = bucketStart[b], e = s + bucketCount[b];
    for (int j = s + t; j < e; j += 256) {
        int u = __builtin_nontemporal_load(recs + j);
        atomicAdd(&cnt[u & 511], 1);
    }
    __syncthreads();
    int nodeBase = b * BSZ;
    for (int n = t; n < BSZ; n += 256) {
        int i = nodeBase + n;
        if (i < N) dinv[i] = rsqrtf((float)cnt[n] + 1.0f);
    }
}

// ---------- prep: g1 = fp16( dinv * (x @ W1) ) -----------------------------
__global__ void prep_kernel(const float* __restrict__ x, const float* __restrict__ W1,
                            const float* __restrict__ dinv, half4* __restrict__ g1h, int N) {
    int i = blockIdx.x * blockDim.x + threadIdx.x;
    if (i >= N) return;
    float d = dinv[i];
    float acc0 = 0.f, acc1 = 0.f, acc2 = 0.f, acc3 = 0.f;
#pragma unroll
    for (int k = 0; k < 9; ++k) {
        float xv = x[i * 9 + k];
        acc0 += xv * W1[k * 4 + 0];
        acc1 += xv * W1[k * 4 + 1];
        acc2 += xv * W1[k * 4 + 2];
        acc3 += xv * W1[k * 4 + 3];
    }
    half4 h;
    h.x = (_Float16)(d * acc0);
    h.y = (_Float16)(d * acc1);
    h.z = (_Float16)(d * acc2);
    h.w = (_Float16)(d * acc3);
    g1h[i] = h;
}

// ---------- agg layer 1 (LDS accumulate) + mid fused -----------------------
__global__ void agg1_kernel(const int* __restrict__ bucketStart, const int* __restrict__ bucketCount,
                            const int* __restrict__ recs, const float* __restrict__ dinv,
                            const half4* __restrict__ g1h, const float* __restrict__ b1,
                            const float* __restrict__ W2, half2v* __restrict__ g2h, int N) {
    __shared__ float acc[4][BSZ + 8];
    int t = threadIdx.x, b = blockIdx.x;
    for (int i = t; i < BSZ; i += 256) {
        acc[0][i] = 0.f; acc[1][i] = 0.f; acc[2][i] = 0.f; acc[3][i] = 0.f;
    }
    __syncthreads();
    int s = bucketStart[b], e = s + bucketCount[b];
    for (int j = s + t; j < e; j += 256) {
        unsigned u = (unsigned)__builtin_nontemporal_load(recs + j);
        int r = u >> 9, cl = u & 511;
        half4 g = g1h[r];
        atomicAdd(&acc[0][cl], (float)g.x);
        atomicAdd(&acc[1][cl], (float)g.y);
        atomicAdd(&acc[2][cl], (float)g.z);
        atomicAdd(&acc[3][cl], (float)g.w);
    }
    __syncthreads();
    int nodeBase = b * BSZ;
    for (int n = t; n < BSZ; n += 256) {
        int i = nodeBase + n;
        if (i >= N) continue;
        half4 self = g1h[i];
        float di = dinv[i];
        float t0 = tanhf(di * (acc[0][n] + (float)self.x) + b1[0]);
        float t1 = tanhf(di * (acc[1][n] + (float)self.y) + b1[1]);
        float t2 = tanhf(di * (acc[2][n] + (float)self.z) + b1[2]);
        float t3 = tanhf(di * (acc[3][n] + (float)self.w) + b1[3]);
        float o0 = t0 * W2[0] + t1 * W2[2] + t2 * W2[4] + t3 * W2[6];
        float o1 = t0 * W2[1] + t1 * W2[3] + t2 * W2[5] + t3 * W2[7];
        half2v g2;
        g2.x = (_Float16)(di * o0);
        g2.y = (_Float16)(di * o1);
        g2h[i] = g2;
    }
}

// ---------- agg layer 2 (LDS accumulate) + final fused ---------------------
__global__ void agg2_kernel(const int* __restrict__ bucketStart, const int* __restrict__ bucketCount,
                            const int* __restrict__ recs, const float* __restrict__ dinv,
                            const half2v* __restrict__ g2h, const float* __restrict__ b2,
                            float* __restrict__ out, int N) {
    __shared__ float acc[2][BSZ + 8];
    int t = threadIdx.x, b = blockIdx.x;
    for (int i = t; i < BSZ; i += 256) { acc[0][i] = 0.f; acc[1][i] = 0.f; }
    __syncthreads();
    int s = bucketStart[b], e = s + bucketCount[b];
    for (int j = s + t; j < e; j += 256) {
        unsigned u = (unsigned)__builtin_nontemporal_load(recs + j);
        int r = u >> 9, cl = u & 511;
        half2v g = g2h[r];
        atomicAdd(&acc[0][cl], (float)g.x);
        atomicAdd(&acc[1][cl], (float)g.y);
    }
    __syncthreads();
    int nodeBase = b * BSZ;
    for (int n = t; n < BSZ; n += 256) {
        int i = nodeBase + n;
        if (i >= N) continue;
        half2v self = g2h[i];
        float di = dinv[i];
        reinterpret_cast<float2*>(out)[i] =
            make_float2(di * (acc[0][n] + (float)self.x) + b2[0],
                        di * (acc[1][n] + (float)self.y) + b2[1]);
    }
}

extern "C" void kernel_launch(void* const* d_in, const int* in_sizes, int n_in,
                              void* d_out, int out_size, void* d_ws, size_t ws_size,
                              hipStream_t stream) {
    const float* x  = (const float*)d_in[0];
    const int*   ei = (const int*)d_in[1];   // [2, E] int32
    const float* W1 = (const float*)d_in[2];
    const float* b1 = (const float*)d_in[3];
    const float* W2 = (const float*)d_in[4];
    const float* b2 = (const float*)d_in[5];
    float* out = (float*)d_out;

    const int N = NN;
    const int E = in_sizes[1] / 2;           // 16,000,000
    const int* row = ei;                     // edge_index[0] = source
    const int* col = ei + E;                 // edge_index[1] = target

    const int nchunks = (E + CHUNK - 1) / CHUNK;          // 977

    // ws layout (16B aligned):
    // bucketCount @0 (4K), bucketStart @4K, gcursor @8K,
    // blkCnt @16K (nchunks*4KB ~ 3.82MB), dinv @16K+4M (2MB),
    // g1h @16K+6M (4MB), g2h @16K+10M (2MB), recs @16K+12M (64MB)  => ~76MB
    char* ws = (char*)d_ws;
    int*    bucketCount = (int*)ws;
    int*    bucketStart = (int*)(ws + 4096);
    int*    gcursor     = (int*)(ws + 8192);
    int*    blkCnt      = (int*)(ws + 16384);
    float*  dinv        = (float*)(ws + 16384 + 4194304ull);
    half4*  g1h         = (half4*)(ws + 16384 + 6291456ull);
    half2v* g2h         = (half2v*)(ws + 16384 + 10485760ull);
    int*    recs        = (int*)(ws + 16384 + 12582912ull);

    (void)hipMemsetAsync(bucketCount, 0, 4096, stream);

    const int ngrid = (N + 255) / 256;                    // 1954

    hist_kernel<<<nchunks, 256, 0, stream>>>(col, bucketCount, blkCnt, E);
    scan_kernel<<<1, 1024, 0, stream>>>(bucketCount, bucketStart, gcursor);
    part_kernel<<<nchunks, 256, 0, stream>>>(row, col, gcursor, blkCnt, recs, E);
    deg_kernel <<<NBK, 256, 0, stream>>>(bucketStart, bucketCount, recs, dinv, N);
    prep_kernel<<<ngrid, 256, 0, stream>>>(x, W1, dinv, g1h, N);
    agg1_kernel<<<NBK, 256, 0, stream>>>(bucketStart, bucketCount, recs, dinv, g1h, b1, W2, g2h, N);
    agg2_kernel<<<NBK, 256, 0, stream>>>(bucketStart, bucketCount, recs, dinv, g2h, b2, out, N);
}